// Round 17
// baseline (46.809 us; speedup 1.0000x reference)
//
#include <hip/hip_runtime.h>
#include <hip/hip_fp16.h>

// Problem constants (match reference)
#define NRAYS 1048576
#define NV 32
#define ND 32
#define NF 6
#define NK 13      // 2F+1
#define RPB 256    // rays per block
#define NTILE_MAX 64

typedef _Float16 h2 __attribute__((ext_vector_type(2)));
typedef _Float16 h8 __attribute__((ext_vector_type(8)));
typedef float f4 __attribute__((ext_vector_type(4)));

__device__ __forceinline__ h2 pack2(float a, float b) {
#if __has_builtin(__builtin_amdgcn_cvt_pkrtz)
    return __builtin_bit_cast(h2, __builtin_amdgcn_cvt_pkrtz(a, b));
#else
    h2 r; r.x = (_Float16)a; r.y = (_Float16)b; return r;
#endif
}
__device__ __forceinline__ float hwsin(float rev) {
#if __has_builtin(__builtin_amdgcn_sinf)
    return __builtin_amdgcn_sinf(rev);
#else
    return __sinf(6.28318530717958647692f * rev);
#endif
}
__device__ __forceinline__ float hwcos(float rev) {
#if __has_builtin(__builtin_amdgcn_cosf)
    return __builtin_amdgcn_cosf(rev);
#else
    return __cosf(6.28318530717958647692f * rev);
#endif
}

// ---------------------------------------------------------------------------
// Kernel A (R14-verified): weights -> MFMA B-fragments (f16), 64 KB image.
// For mfma_f32_16x16x32_f16: lane l holds B[k=(l>>4)*8+j][col=l&15], j=0..7.
__global__ void pack_weights_kernel(const float* __restrict__ weights,
                                    unsigned* __restrict__ wfrag)
{
    int idx = blockIdx.x * 256 + threadIdx.x;  // 0 .. 16383
    if (idx >= 16384) return;
    int v = idx >> 9;
    int r = idx & 511;
    int dhalf = r >> 8;
    int r2 = r & 255;
    int lane = r2 >> 2;
    int e = r2 & 3;
    int d = dhalf * 16 + (lane & 15);
    int k0 = (lane >> 4) * 8 + 2 * e;
    const float* wp = weights + v * (ND * NK) + d * NK;
    float w0 = (k0 < NK) ? wp[k0] : 0.f;
    float w1 = (k0 + 1 < NK) ? wp[k0 + 1] : 0.f;
    wfrag[idx] = __builtin_bit_cast(unsigned, pack2(w0, w1));
}

// ---------------------------------------------------------------------------
// Main kernel. Block = 256 contiguous rays, 256 threads, 4 blocks/CU.
// P1: counting-sort by vid; basis once per ray -> s_bt[slot] (64B rows, K=32).
// P2: per 16-row vid-uniform tile: b128 A-frag + 2 L1 B-frags + 2 MFMA;
//     C (f32->f16) masked-written to s_c[slot] rows.
// P3: inverse-perm read of s_c + R16-style coalesced f4 stores.
__global__ __launch_bounds__(256, 4) void VideoEmbedding_kernel(
    const float* __restrict__ times,
    const int* __restrict__ vids,
    const uint4* __restrict__ wfrag,
    float* __restrict__ out)
{
    __shared__ __align__(16) _Float16 s_bt[(RPB + 16) * 32];  // 17408 B
    __shared__ __align__(16) _Float16 s_c[RPB * 32];          // 16384 B
    __shared__ unsigned short s_inv[RPB];                     //   512 B
    __shared__ int hist[NV];
    __shared__ unsigned ttab[NTILE_MAX];
    __shared__ int s_nT;

    const int tid = threadIdx.x;
    const int rbase = blockIdx.x * RPB;

    if (tid < NV) hist[tid] = 0;
    __syncthreads();

    const float t = times[rbase + tid];
    const int vid = vids[rbase + tid];
    atomicAdd(&hist[vid], 1);
    __syncthreads();

    if (tid < NV) {
        int c = hist[tid];
        int sum = c;
#pragma unroll
        for (int off = 1; off < NV; off <<= 1) {
            int n = __shfl_up(sum, off, NV);
            if (tid >= off) sum += n;
        }
        int excl = sum - c;
        hist[tid] = excl;  // becomes scatter cursor
        int nt = (c + 15) >> 4;
        int tsum = nt;
#pragma unroll
        for (int off = 1; off < NV; off <<= 1) {
            int n = __shfl_up(tsum, off, NV);
            if (tid >= off) tsum += n;
        }
        int texcl = tsum - nt;
        if (tid == NV - 1) s_nT = tsum;
        unsigned endv = (unsigned)(excl + c);
        for (int s = 0; s < nt; ++s)
            ttab[texcl + s] =
                ((unsigned)tid << 22) | (endv << 11) | (unsigned)(excl + 16 * s);
    }
    if (tid < 64) {  // zero the 16 overhang basis rows (1024 B)
        uint4 zz; zz.x = zz.y = zz.z = zz.w = 0u;
        reinterpret_cast<uint4*>(s_bt + RPB * 32)[tid] = zz;
    }
    __syncthreads();

    {   // scatter: sorted slot, inverse perm, basis row (32 halves, k>=14 = 0)
        int slot = atomicAdd(&hist[vid], 1);
        s_inv[tid] = (unsigned short)slot;
        float sv[NF], cv[NF];
        sv[0] = hwsin(0.5f * t);
        cv[0] = hwcos(0.5f * t);
#pragma unroll
        for (int j = 1; j < NF; ++j) {
            float sj = sv[j - 1], cj = cv[j - 1];
            sv[j] = 2.f * sj * cj;
            cv[j] = fmaf(-2.f * sj, sj, 1.f);
        }
        uint4 lo, hi, zz;
        lo.x = __builtin_bit_cast(unsigned, pack2(1.0f, sv[0]));
        lo.y = __builtin_bit_cast(unsigned, pack2(sv[1], sv[2]));
        lo.z = __builtin_bit_cast(unsigned, pack2(sv[3], sv[4]));
        lo.w = __builtin_bit_cast(unsigned, pack2(sv[5], cv[0]));
        hi.x = __builtin_bit_cast(unsigned, pack2(cv[1], cv[2]));
        hi.y = __builtin_bit_cast(unsigned, pack2(cv[3], cv[4]));
        hi.z = __builtin_bit_cast(unsigned, pack2(cv[5], 0.0f));
        hi.w = 0u;
        zz.x = zz.y = zz.z = zz.w = 0u;
        uint4* row = reinterpret_cast<uint4*>(s_bt + slot * 32);
        row[0] = lo;
        row[1] = hi;
        row[2] = zz;
        row[3] = zz;
    }
    __syncthreads();

    // -------- phase 2: MFMA per tile, C -> s_c (f16, store-masked) --------
    const int lane = tid & 63;
    const int lrow = lane & 15;
    const int lkc = lane >> 4;
    const int T = s_nT;

    for (int tt = tid >> 6; tt < T; tt += 4) {
        const unsigned e = ttab[tt];
        const int rowstart = (int)(e & 0x7FFu);
        const int rend = (int)((e >> 11) & 0x7FFu);
        const int vv = (int)(e >> 22);

        h8 a = *reinterpret_cast<const h8*>(
            &s_bt[(rowstart + lrow) * 32 + lkc * 8]);
        uint4 b0u = wfrag[(vv * 2 + 0) * 64 + lane];
        uint4 b1u = wfrag[(vv * 2 + 1) * 64 + lane];

        f4 z = {0.f, 0.f, 0.f, 0.f};
        f4 c0 = __builtin_amdgcn_mfma_f32_16x16x32_f16(
            a, __builtin_bit_cast(h8, b0u), z, 0, 0, 0);
        f4 c1 = __builtin_amdgcn_mfma_f32_16x16x32_f16(
            a, __builtin_bit_cast(h8, b1u), z, 0, 0, 0);

#pragma unroll
        for (int j = 0; j < 4; ++j) {
            const int srow = rowstart + lkc * 4 + j;
            if (srow < rend) {
                s_c[srow * 32 + lrow] = (_Float16)c0[j];
                s_c[srow * 32 + lrow + 16] = (_Float16)c1[j];
            }
        }
    }
    __syncthreads();

    // -------- phase 3: gather via inverse perm + coalesced f4 stores --------
    const int q = tid & 7;
    const int g = tid >> 3;
#pragma unroll
    for (int p = 0; p < 8; ++p) {
        const int r = p * 32 + g;
        const int slot = s_inv[r];
        const uint2 cw =
            *reinterpret_cast<const uint2*>(&s_c[slot * 32 + q * 4]);
        const h2 p0 = __builtin_bit_cast(h2, cw.x);
        const h2 p1 = __builtin_bit_cast(h2, cw.y);
        f4 res;
        res.x = (float)p0.x;
        res.y = (float)p0.y;
        res.z = (float)p1.x;
        res.w = (float)p1.y;
        reinterpret_cast<f4*>(out)[(size_t)(rbase + r) * 8 + q] = res;
    }
}

extern "C" void kernel_launch(void* const* d_in, const int* in_sizes, int n_in,
                              void* d_out, int out_size, void* d_ws, size_t ws_size,
                              hipStream_t stream) {
    const float* times = (const float*)d_in[0];
    const int* vids = (const int*)d_in[1];
    const float* weights = (const float*)d_in[2];
    float* out = (float*)d_out;
    unsigned* wfrag = (unsigned*)d_ws;

    hipLaunchKernelGGL(pack_weights_kernel, dim3(64), dim3(256), 0, stream,
                       weights, wfrag);
    // 4096 blocks x 256 rays; 4 blocks/CU (34.3 KB LDS).
    hipLaunchKernelGGL(VideoEmbedding_kernel, dim3(4096), dim3(256), 0, stream,
                       times, vids, (const uint4*)wfrag, out);
}

// Round 18
// 36.306 us; speedup vs baseline: 1.2893x; 1.2893x over previous
//
#include <hip/hip_runtime.h>
#include <hip/hip_fp16.h>

// Problem constants (match reference)
#define NRAYS 1048576
#define NV 32
#define ND 32
#define NF 6
#define NK 13      // 2F+1
#define RPB 1024   // rays per block
#define NTILE_MAX 96

typedef _Float16 h2 __attribute__((ext_vector_type(2)));
typedef _Float16 h8 __attribute__((ext_vector_type(8)));
typedef float f4 __attribute__((ext_vector_type(4)));

__device__ __forceinline__ h2 pack2(float a, float b) {
#if __has_builtin(__builtin_amdgcn_cvt_pkrtz)
    return __builtin_bit_cast(h2, __builtin_amdgcn_cvt_pkrtz(a, b));
#else
    h2 r; r.x = (_Float16)a; r.y = (_Float16)b; return r;
#endif
}
__device__ __forceinline__ float hwsin(float rev) {
#if __has_builtin(__builtin_amdgcn_sinf)
    return __builtin_amdgcn_sinf(rev);
#else
    return __sinf(6.28318530717958647692f * rev);
#endif
}
__device__ __forceinline__ float hwcos(float rev) {
#if __has_builtin(__builtin_amdgcn_cosf)
    return __builtin_amdgcn_cosf(rev);
#else
    return __cosf(6.28318530717958647692f * rev);
#endif
}

// ---------------------------------------------------------------------------
// Kernel A (R14-verified): weights -> MFMA B-fragments (f16), 64 KB image.
// For mfma_f32_16x16x32_f16: lane l holds B[k=(l>>4)*8+j][col=l&15], j=0..7;
// k >= 13 zeroed (this also makes the 16-wide A-row overlap read benign).
__global__ void pack_weights_kernel(const float* __restrict__ weights,
                                    unsigned* __restrict__ wfrag)
{
    int idx = blockIdx.x * 256 + threadIdx.x;  // 0 .. 16383
    if (idx >= 16384) return;
    int v = idx >> 9;
    int r = idx & 511;
    int dhalf = r >> 8;
    int r2 = r & 255;
    int lane = r2 >> 2;
    int e = r2 & 3;
    int d = dhalf * 16 + (lane & 15);
    int k0 = (lane >> 4) * 8 + 2 * e;
    const float* wp = weights + v * (ND * NK) + d * NK;
    float w0 = (k0 < NK) ? wp[k0] : 0.f;
    float w1 = (k0 + 1 < NK) ? wp[k0 + 1] : 0.f;
    wfrag[idx] = __builtin_bit_cast(unsigned, pack2(w0, w1));
}

// ---------------------------------------------------------------------------
// Main kernel. Block = 1024 contiguous rays, 256 threads, 4 blocks/CU.
// P1: counting-sort by vid; basis once per ray -> s_bt (16-half rows).
// P2: SOFTWARE-PIPELINED tile loop (prefetch t+1's ttab/A/B/meta before
//     computing t) — fixes R14's latency-exposed serial tile chain.
//     Per tile: 1 A b128 (LDS) + 2 B uint4 (L1) + 2 MFMA + 8 masked dword
//     stores (wave covers 16 full 128B lines).
__global__ __launch_bounds__(256, 4) void VideoEmbedding_kernel(
    const float* __restrict__ times,
    const int* __restrict__ vids,
    const uint4* __restrict__ wfrag,
    float* __restrict__ out)
{
    __shared__ __align__(16) _Float16 s_bt[(RPB + 20) * 16];  // 33408 B
    __shared__ unsigned s_meta[RPB + 20];                     //  4176 B
    __shared__ int hist[NV];
    __shared__ unsigned ttab[NTILE_MAX];
    __shared__ int s_nT;

    const int tid = threadIdx.x;
    const int rbase = blockIdx.x * RPB;

    if (tid < NV) hist[tid] = 0;
    if (tid >= 64 && tid < 104) {  // zero 20 pad rows (40 x 16 B)
        uint4 zz = {};
        reinterpret_cast<uint4*>(s_bt + RPB * 16)[tid - 64] = zz;
    }
    __syncthreads();

    float t[4];
    int v[4];
#pragma unroll
    for (int it = 0; it < 4; ++it) {
        int lid = it * 256 + tid;
        t[it] = times[rbase + lid];
        v[it] = vids[rbase + lid];
        atomicAdd(&hist[v[it]], 1);
    }
    __syncthreads();

    if (tid < NV) {
        int c = hist[tid];
        int sum = c;
#pragma unroll
        for (int off = 1; off < NV; off <<= 1) {
            int n = __shfl_up(sum, off, NV);
            if (tid >= off) sum += n;
        }
        int excl = sum - c;
        hist[tid] = excl;  // becomes scatter cursor
        int nt = (c + 15) >> 4;
        int tsum = nt;
#pragma unroll
        for (int off = 1; off < NV; off <<= 1) {
            int n = __shfl_up(tsum, off, NV);
            if (tid >= off) tsum += n;
        }
        int texcl = tsum - nt;
        if (tid == NV - 1) s_nT = tsum;
        unsigned endv = (unsigned)(excl + c);
        for (int s = 0; s < nt; ++s)
            ttab[texcl + s] =
                ((unsigned)tid << 22) | (endv << 11) | (unsigned)(excl + 16 * s);
    }
    __syncthreads();

#pragma unroll
    for (int it = 0; it < 4; ++it) {
        int slot = atomicAdd(&hist[v[it]], 1);
        s_meta[slot] = (unsigned)(it * 256 + tid);
        float sv[NF], cv[NF];
        sv[0] = hwsin(0.5f * t[it]);
        cv[0] = hwcos(0.5f * t[it]);
#pragma unroll
        for (int j = 1; j < NF; ++j) {
            float sj = sv[j - 1], cj = cv[j - 1];
            sv[j] = 2.f * sj * cj;
            cv[j] = fmaf(-2.f * sj, sj, 1.f);
        }
        uint4 lo, hi;
        lo.x = __builtin_bit_cast(unsigned, pack2(1.0f, sv[0]));
        lo.y = __builtin_bit_cast(unsigned, pack2(sv[1], sv[2]));
        lo.z = __builtin_bit_cast(unsigned, pack2(sv[3], sv[4]));
        lo.w = __builtin_bit_cast(unsigned, pack2(sv[5], cv[0]));
        hi.x = __builtin_bit_cast(unsigned, pack2(cv[1], cv[2]));
        hi.y = __builtin_bit_cast(unsigned, pack2(cv[3], cv[4]));
        hi.z = __builtin_bit_cast(unsigned, pack2(cv[5], 0.0f));
        hi.w = 0u;
        uint4* row = reinterpret_cast<uint4*>(s_bt + slot * 16);
        row[0] = lo;
        row[1] = hi;
    }
    __syncthreads();

    // -------- P2: pipelined MFMA tile loop --------
    const int lane = tid & 63;
    const int lrow = lane & 15;
    const int lkc = lane >> 4;
    const int T = s_nT;
    int tt = tid >> 6;

    unsigned e0 = 0;
    h8 a0 = {0, 0, 0, 0, 0, 0, 0, 0};
    uint4 b00 = {}, b10 = {};
    unsigned m00 = 0, m01 = 0, m02 = 0, m03 = 0;
    if (tt < T) {
        e0 = ttab[tt];
        const int rs = (int)(e0 & 0x7FFu);
        a0 = *reinterpret_cast<const h8*>(&s_bt[(rs + lrow) * 16 + lkc * 8]);
        const int vv = (int)(e0 >> 22);
        b00 = wfrag[(vv * 2 + 0) * 64 + lane];
        b10 = wfrag[(vv * 2 + 1) * 64 + lane];
        const int mb = rs + lkc * 4;
        m00 = s_meta[mb]; m01 = s_meta[mb + 1];
        m02 = s_meta[mb + 2]; m03 = s_meta[mb + 3];
    }

    while (tt < T) {
        const int tn = tt + 4;
        unsigned e1 = 0;
        h8 a1 = {0, 0, 0, 0, 0, 0, 0, 0};
        uint4 b01 = {}, b11 = {};
        unsigned m10 = 0, m11 = 0, m12 = 0, m13 = 0;
        if (tn < T) {  // prefetch everything for tile tn
            e1 = ttab[tn];
            const int rs = (int)(e1 & 0x7FFu);
            a1 = *reinterpret_cast<const h8*>(&s_bt[(rs + lrow) * 16 + lkc * 8]);
            const int vv = (int)(e1 >> 22);
            b01 = wfrag[(vv * 2 + 0) * 64 + lane];
            b11 = wfrag[(vv * 2 + 1) * 64 + lane];
            const int mb = rs + lkc * 4;
            m10 = s_meta[mb]; m11 = s_meta[mb + 1];
            m12 = s_meta[mb + 2]; m13 = s_meta[mb + 3];
        }

        {   // compute + store tile tt
            const int rs = (int)(e0 & 0x7FFu);
            const int rend = (int)((e0 >> 11) & 0x7FFu);
            f4 z = {0.f, 0.f, 0.f, 0.f};
            f4 c0 = __builtin_amdgcn_mfma_f32_16x16x32_f16(
                a0, __builtin_bit_cast(h8, b00), z, 0, 0, 0);
            f4 c1 = __builtin_amdgcn_mfma_f32_16x16x32_f16(
                a0, __builtin_bit_cast(h8, b10), z, 0, 0, 0);
            const int sr = rs + lkc * 4;
            if (sr + 0 < rend) {
                float* o = out + (size_t)(rbase + (int)m00) * 32 + lrow;
                o[0] = c0[0]; o[16] = c1[0];
            }
            if (sr + 1 < rend) {
                float* o = out + (size_t)(rbase + (int)m01) * 32 + lrow;
                o[0] = c0[1]; o[16] = c1[1];
            }
            if (sr + 2 < rend) {
                float* o = out + (size_t)(rbase + (int)m02) * 32 + lrow;
                o[0] = c0[2]; o[16] = c1[2];
            }
            if (sr + 3 < rend) {
                float* o = out + (size_t)(rbase + (int)m03) * 32 + lrow;
                o[0] = c0[3]; o[16] = c1[3];
            }
        }

        tt = tn;
        e0 = e1; a0 = a1; b00 = b01; b10 = b11;
        m00 = m10; m01 = m11; m02 = m12; m03 = m13;
    }
}

extern "C" void kernel_launch(void* const* d_in, const int* in_sizes, int n_in,
                              void* d_out, int out_size, void* d_ws, size_t ws_size,
                              hipStream_t stream) {
    const float* times = (const float*)d_in[0];
    const int* vids = (const int*)d_in[1];
    const float* weights = (const float*)d_in[2];
    float* out = (float*)d_out;
    unsigned* wfrag = (unsigned*)d_ws;

    hipLaunchKernelGGL(pack_weights_kernel, dim3(64), dim3(256), 0, stream,
                       weights, wfrag);
    // 1024 blocks x 1024 rays; 4 blocks/CU (~37 KB LDS).
    hipLaunchKernelGGL(VideoEmbedding_kernel, dim3(1024), dim3(256), 0, stream,
                       times, vids, (const uint4*)wfrag, out);
}

// Round 19
// 33.504 us; speedup vs baseline: 1.3971x; 1.0836x over previous
//
#include <hip/hip_runtime.h>
#include <hip/hip_fp16.h>

// Problem constants (match reference)
#define NRAYS 1048576
#define NV 32
#define ND 32
#define NF 6
#define NK 13  // 2F+1

typedef _Float16 h2 __attribute__((ext_vector_type(2)));
typedef float f4 __attribute__((ext_vector_type(4)));

__device__ __forceinline__ float fdot2acc(h2 a, h2 b, float c) {
#if __has_builtin(__builtin_amdgcn_fdot2)
    return __builtin_amdgcn_fdot2(a, b, c, false);
#else
    return c + (float)a.x * (float)b.x + (float)a.y * (float)b.y;
#endif
}

__device__ __forceinline__ h2 pack2(float a, float b) {
#if __has_builtin(__builtin_amdgcn_cvt_pkrtz)
    return __builtin_bit_cast(h2, __builtin_amdgcn_cvt_pkrtz(a, b));
#else
    h2 r; r.x = (_Float16)a; r.y = (_Float16)b; return r;
#endif
}

__device__ __forceinline__ float hwsin(float rev) {
#if __has_builtin(__builtin_amdgcn_sinf)
    return __builtin_amdgcn_sinf(rev);
#else
    return __sinf(6.28318530717958647692f * rev);
#endif
}
__device__ __forceinline__ float hwcos(float rev) {
#if __has_builtin(__builtin_amdgcn_cosf)
    return __builtin_amdgcn_cosf(rev);
#else
    return __cosf(6.28318530717958647692f * rev);
#endif
}

__device__ __forceinline__ void make_basis(float t, h2 bp[7]) {
    float sv[NF], cv[NF];
    sv[0] = hwsin(0.5f * t);
    cv[0] = hwcos(0.5f * t);
#pragma unroll
    for (int j = 1; j < NF; ++j) {
        float sj = sv[j - 1], cj = cv[j - 1];
        sv[j] = 2.f * sj * cj;
        cv[j] = fmaf(-2.f * sj, sj, 1.f);
    }
    bp[0] = pack2(1.0f, sv[0]);
    bp[1] = pack2(sv[1], sv[2]);
    bp[2] = pack2(sv[3], sv[4]);
    bp[3] = pack2(sv[5], cv[0]);
    bp[4] = pack2(cv[1], cv[2]);
    bp[5] = pack2(cv[3], cv[4]);
    bp[6] = pack2(cv[5], 0.0f);  // pad half must be 0
}

// ---------------------------------------------------------------------------
// Kernel A: pack f32 weights into the v&7-XOR-swizzled f16 image (see R5).
__global__ void pack_weights_kernel(const float* __restrict__ weights,
                                    unsigned* __restrict__ wpack)
{
    int j = blockIdx.x * 256 + threadIdx.x;  // 0 .. 7167 (dwords)
    if (j >= NV * 7 * 32) return;
    int v = j / 224;
    int r = j - v * 224;
    int i = r >> 5;
    int c = r & 31;
    int pos = c >> 2;
    int e = c & 3;
    int q = pos ^ (v & 7);
    int d = 4 * q + e;
    float w0 = weights[v * (ND * NK) + d * NK + 2 * i];
    float w1 = (2 * i + 1 < NK) ? weights[v * (ND * NK) + d * NK + 2 * i + 1] : 0.f;
    wpack[j] = __builtin_bit_cast(unsigned, pack2(w0, w1));
}

// ---------------------------------------------------------------------------
// Main kernel (R11, best measured: 33.77us). Block owns 512 contiguous rays.
// ALL global loads issue in the prologue (stores-only vmcnt queue in loop).
// 8 threads per ray: thread q owns d = 4q..4q+3. Weight regs double-buffered,
// plain (cached) f4 stores.
__global__ __launch_bounds__(256, 5) void VideoEmbedding_kernel(
    const float* __restrict__ times,
    const int* __restrict__ vids,
    const unsigned* __restrict__ wpack,
    float* __restrict__ out)
{
    __shared__ _Float16 wl[NV * 7 * ND * 2];   // 28672 B
    __shared__ float s_t[512];                 // 2048 B
    __shared__ unsigned char s_v[512];         // 512 B   -> 31232 B total

    const int tid = threadIdx.x;
    const int rbase = blockIdx.x * 512;

    // -------- prologue: every global load, all before any store --------
    uint4 wst[7];
    {
        const uint4* src = reinterpret_cast<const uint4*>(wpack);
#pragma unroll
        for (int j = 0; j < 7; ++j)
            wst[j] = src[tid + j * 256];
    }
    const float t0 = times[rbase + tid];
    const float t1 = times[rbase + 256 + tid];
    const int v0i = vids[rbase + tid];
    const int v1i = vids[rbase + 256 + tid];

    {
        uint4* dst = reinterpret_cast<uint4*>(wl);
#pragma unroll
        for (int j = 0; j < 7; ++j)
            dst[tid + j * 256] = wst[j];
    }
    s_t[tid] = t0;
    s_t[tid + 256] = t1;
    s_v[tid] = (unsigned char)v0i;
    s_v[tid + 256] = (unsigned char)v1i;
    __syncthreads();

    const int q = tid & 7;
    const int g = tid >> 3;  // ray-group 0..31; slot = p*32+g, ray = rbase+slot

    uint4 wA[7], wB[7];
    {
        const int v = s_v[g];
        const unsigned b = (unsigned)v * 448u + (unsigned)(q ^ (v & 7)) * 8u;
#pragma unroll
        for (int i = 0; i < 7; ++i)
            wA[i] = *reinterpret_cast<const uint4*>(&wl[b + i * 64]);
    }

#define ITER(P, WCUR, WNEXT)                                                  \
    {                                                                         \
        if ((P) < 15) {  /* prefetch weights for slot P+1 */                  \
            const int nv = s_v[((P) + 1) * 32 + g];                           \
            const unsigned nb =                                               \
                (unsigned)nv * 448u + (unsigned)(q ^ (nv & 7)) * 8u;          \
            _Pragma("unroll")                                                 \
            for (int i = 0; i < 7; ++i)                                       \
                WNEXT[i] = *reinterpret_cast<const uint4*>(&wl[nb + i * 64]); \
        }                                                                     \
        const float t = s_t[(P) * 32 + g];                                    \
        h2 bp[7];                                                             \
        make_basis(t, bp);                                                    \
        float a0 = 0.f, a1 = 0.f, a2 = 0.f, a3 = 0.f;                         \
        _Pragma("unroll")                                                     \
        for (int i = 0; i < 7; ++i) {                                         \
            a0 = fdot2acc(__builtin_bit_cast(h2, WCUR[i].x), bp[i], a0);      \
            a1 = fdot2acc(__builtin_bit_cast(h2, WCUR[i].y), bp[i], a1);      \
            a2 = fdot2acc(__builtin_bit_cast(h2, WCUR[i].z), bp[i], a2);      \
            a3 = fdot2acc(__builtin_bit_cast(h2, WCUR[i].w), bp[i], a3);      \
        }                                                                     \
        f4 res;                                                               \
        res.x = a0; res.y = a1; res.z = a2; res.w = a3;                       \
        reinterpret_cast<f4*>(out)[(size_t)(rbase + (P) * 32 + g) * 8 + q] =  \
            res;                                                              \
    }

    for (int p = 0; p < 16; p += 2) {
        ITER(p, wA, wB)
        ITER(p + 1, wB, wA)
    }
#undef ITER
}

extern "C" void kernel_launch(void* const* d_in, const int* in_sizes, int n_in,
                              void* d_out, int out_size, void* d_ws, size_t ws_size,
                              hipStream_t stream) {
    const float* times = (const float*)d_in[0];
    const int* vids = (const int*)d_in[1];
    const float* weights = (const float*)d_in[2];
    float* out = (float*)d_out;
    unsigned* wpack = (unsigned*)d_ws;

    hipLaunchKernelGGL(pack_weights_kernel, dim3(28), dim3(256), 0, stream,
                       weights, wpack);
    // 2048 blocks x 512 contiguous rays; 5 blocks/CU (31232 B LDS).
    hipLaunchKernelGGL(VideoEmbedding_kernel, dim3(2048), dim3(256), 0, stream,
                       times, vids, wpack, out);
}